// Round 1
// baseline (460.887 us; speedup 1.0000x reference)
//
#include <hip/hip_runtime.h>
#include <math.h>

#define NN 4096
#define DD 128
#define HH 4
#define NEG 9.0e15f
#define BI 8

// ---------------- K1: ht[h][i][d] = (h@W)[i][h*128+d] ----------------
__global__ __launch_bounds__(512) void k_htgemm(const float* __restrict__ h,
                                                const float* __restrict__ W,
                                                float* __restrict__ ht) {
  __shared__ float hs[16][128];
  const int i0 = blockIdx.x * 16;
  for (int idx = threadIdx.x; idx < 16 * 128; idx += 512)
    hs[idx >> 7][idx & 127] = h[(i0 + (idx >> 7)) * 128 + (idx & 127)];
  __syncthreads();
  const int c = threadIdx.x;  // 0..511 output column
  float acc[16];
#pragma unroll
  for (int r = 0; r < 16; ++r) acc[r] = 0.f;
  for (int k = 0; k < 128; ++k) {
    const float w = W[k * 512 + c];
#pragma unroll
    for (int r = 0; r < 16; ++r) acc[r] = fmaf(hs[r][k], w, acc[r]);
  }
  const int hc = c >> 7, d = c & 127;
#pragma unroll
  for (int r = 0; r < 16; ++r)
    ht[hc * (NN * 128) + (i0 + r) * 128 + d] = acc[r];
}

// ---------------- K1b: src/tgt = ht . a ----------------
__global__ __launch_bounds__(64) void k_srctgt(const float* __restrict__ ht,
                                               const float* __restrict__ a,
                                               float* __restrict__ src,
                                               float* __restrict__ tgt) {
  const int b = blockIdx.x;  // b = h*N + i
  const int hh = b >> 12;    // / 4096
  const int lane = threadIdx.x;
  const float x1 = ht[b * 128 + lane];
  const float x2 = ht[b * 128 + 64 + lane];
  float s = x1 * a[hh * 256 + lane] + x2 * a[hh * 256 + 64 + lane];
  float t = x1 * a[hh * 256 + 128 + lane] + x2 * a[hh * 256 + 192 + lane];
#pragma unroll
  for (int off = 32; off >= 1; off >>= 1) {
    s += __shfl_xor(s, off, 64);
    t += __shfl_xor(t, off, 64);
  }
  if (lane == 0) { src[b] = s; tgt[b] = t; }
}

// ---------------- K2: fused attention (2-pass softmax + PV + delta) ----------------
__global__ __launch_bounds__(256) void k_attn(
    const float* __restrict__ ht, const int* __restrict__ adj,
    const float* __restrict__ pos, const float* __restrict__ src,
    const float* __restrict__ tgt, float* __restrict__ hp,
    float* __restrict__ out_pos) {
  __shared__ float p_s[BI * HH][256];
  __shared__ float pos_s[256][3];
  __shared__ float pix[BI], piy[BI], piz[BI];
  __shared__ float src_s[BI][HH];
  __shared__ float M_s[BI][HH], Li_s[BI][HH];
  __shared__ float mw[4][BI * HH], lw[4][BI * HH];

  const int tid = threadIdx.x;
  const int i0 = blockIdx.x * BI;
  if (tid < BI) {
    pix[tid] = pos[(i0 + tid) * 3];
    piy[tid] = pos[(i0 + tid) * 3 + 1];
    piz[tid] = pos[(i0 + tid) * 3 + 2];
  }
  if (tid < BI * HH) src_s[tid >> 2][tid & 3] = src[(tid & 3) * NN + i0 + (tid >> 2)];
  __syncthreads();

  // ---- pass 1: online (max, sum) per (bi, h) ----
  float m_t[BI][HH], l_t[BI][HH];
#pragma unroll
  for (int bi = 0; bi < BI; ++bi)
#pragma unroll
    for (int hh = 0; hh < HH; ++hh) { m_t[bi][hh] = -1e38f; l_t[bi][hh] = 0.f; }

  for (int j = tid; j < NN; j += 256) {
    const float pjx = pos[j * 3], pjy = pos[j * 3 + 1], pjz = pos[j * 3 + 2];
    float tj[HH];
#pragma unroll
    for (int hh = 0; hh < HH; ++hh) tj[hh] = tgt[hh * NN + j];
#pragma unroll
    for (int bi = 0; bi < BI; ++bi) {
      const int av = adj[(i0 + bi) * NN + j];
      const float dx = pix[bi] - pjx, dy = piy[bi] - pjy, dz = piz[bi] - pjz;
      const float dist = sqrtf(dx * dx + dy * dy + dz * dz);
#pragma unroll
      for (int hh = 0; hh < HH; ++hh) {
        float e = src_s[bi][hh] + tj[hh] - dist;
        e = e > 0.f ? e : 0.2f * e;
        e = av > 0 ? e : -NEG;
        const float m = m_t[bi][hh];
        if (e <= m) {
          l_t[bi][hh] += __expf(e - m);
        } else {
          l_t[bi][hh] = l_t[bi][hh] * __expf(m - e) + 1.f;
          m_t[bi][hh] = e;
        }
      }
    }
  }
  // wave-level combine
#pragma unroll
  for (int off = 32; off >= 1; off >>= 1) {
#pragma unroll
    for (int bi = 0; bi < BI; ++bi)
#pragma unroll
      for (int hh = 0; hh < HH; ++hh) {
        const float om = __shfl_xor(m_t[bi][hh], off, 64);
        const float ol = __shfl_xor(l_t[bi][hh], off, 64);
        const float nm = fmaxf(m_t[bi][hh], om);
        l_t[bi][hh] = l_t[bi][hh] * __expf(m_t[bi][hh] - nm) + ol * __expf(om - nm);
        m_t[bi][hh] = nm;
      }
  }
  const int wid = tid >> 6, lane = tid & 63;
  if (lane == 0) {
#pragma unroll
    for (int bi = 0; bi < BI; ++bi)
#pragma unroll
      for (int hh = 0; hh < HH; ++hh) {
        mw[wid][bi * HH + hh] = m_t[bi][hh];
        lw[wid][bi * HH + hh] = l_t[bi][hh];
      }
  }
  __syncthreads();
  if (tid < BI * HH) {
    float m = mw[0][tid], l = lw[0][tid];
#pragma unroll
    for (int w = 1; w < 4; ++w) {
      const float om = mw[w][tid], ol = lw[w][tid];
      const float nm = fmaxf(m, om);
      l = l * __expf(m - nm) + ol * __expf(om - nm);
      m = nm;
    }
    M_s[tid >> 2][tid & 3] = m;
    Li_s[tid >> 2][tid & 3] = 1.f / l;
  }
  __syncthreads();

  // ---- pass 2: p = exp(e-M)/L ; PV accumulate + delta accumulate ----
  const int h_ = tid >> 6;        // head owned for PV (one per wave)
  const int t6 = tid & 63;
  const int bih = t6 >> 5;        // which half of the 8 rows
  const int d0 = (t6 & 31) * 4;   // 4 consecutive d
  float acc[4][4];
#pragma unroll
  for (int a1 = 0; a1 < 4; ++a1)
#pragma unroll
    for (int a2 = 0; a2 < 4; ++a2) acc[a1][a2] = 0.f;

  const int g_bi = tid >> 5;  // delta group: row bi (32 lanes each)
  const int l32 = tid & 31;
  float dax = 0.f, day = 0.f, daz = 0.f;

  for (int c = 0; c < NN / 256; ++c) {
    const int j = c * 256 + tid;
    {
      const float pjx = pos[j * 3], pjy = pos[j * 3 + 1], pjz = pos[j * 3 + 2];
      pos_s[tid][0] = pjx; pos_s[tid][1] = pjy; pos_s[tid][2] = pjz;
      float tj[HH];
#pragma unroll
      for (int hh = 0; hh < HH; ++hh) tj[hh] = tgt[hh * NN + j];
#pragma unroll
      for (int bi = 0; bi < BI; ++bi) {
        const int av = adj[(i0 + bi) * NN + j];
        const float dx = pix[bi] - pjx, dy = piy[bi] - pjy, dz = piz[bi] - pjz;
        const float dist = sqrtf(dx * dx + dy * dy + dz * dz);
#pragma unroll
        for (int hh = 0; hh < HH; ++hh) {
          float e = src_s[bi][hh] + tj[hh] - dist;
          e = e > 0.f ? e : 0.2f * e;
          e = av > 0 ? e : -NEG;
          p_s[bi * HH + hh][tid] = __expf(e - M_s[bi][hh]) * Li_s[bi][hh];
        }
      }
    }
    __syncthreads();
    // PV
    const float* htp = ht + h_ * (NN * 128) + (c * 256) * 128 + d0;
    for (int jj = 0; jj < 256; ++jj) {
      const float4 hv = *(const float4*)(htp + jj * 128);
#pragma unroll
      for (int bl = 0; bl < 4; ++bl) {
        const float p = p_s[(bih * 4 + bl) * HH + h_][jj];
        acc[bl][0] = fmaf(p, hv.x, acc[bl][0]);
        acc[bl][1] = fmaf(p, hv.y, acc[bl][1]);
        acc[bl][2] = fmaf(p, hv.z, acc[bl][2]);
        acc[bl][3] = fmaf(p, hv.w, acc[bl][3]);
      }
    }
    // delta
#pragma unroll
    for (int k = 0; k < 8; ++k) {
      const int jj = l32 + 32 * k;
      const float am = 0.25f * (p_s[g_bi * HH + 0][jj] + p_s[g_bi * HH + 1][jj] +
                                p_s[g_bi * HH + 2][jj] + p_s[g_bi * HH + 3][jj]);
      dax = fmaf(am, pix[g_bi] - pos_s[jj][0], dax);
      day = fmaf(am, piy[g_bi] - pos_s[jj][1], day);
      daz = fmaf(am, piz[g_bi] - pos_s[jj][2], daz);
    }
    __syncthreads();
  }

  // write per-head normalized PV partials
#pragma unroll
  for (int bl = 0; bl < 4; ++bl) {
    float4 v;
    v.x = acc[bl][0]; v.y = acc[bl][1]; v.z = acc[bl][2]; v.w = acc[bl][3];
    *(float4*)&hp[h_ * (NN * 128) + (i0 + bih * 4 + bl) * 128 + d0] = v;
  }
  // delta: reduce over the 32 lanes of the row group
#pragma unroll
  for (int off = 16; off >= 1; off >>= 1) {
    dax += __shfl_xor(dax, off, 64);
    day += __shfl_xor(day, off, 64);
    daz += __shfl_xor(daz, off, 64);
  }
  if (l32 == 0) {
    const int i = i0 + g_bi;
    out_pos[i * 3 + 0] = pos[i * 3 + 0] + dax;
    out_pos[i * 3 + 1] = pos[i * 3 + 1] + day;
    out_pos[i * 3 + 2] = pos[i * 3 + 2] + daz;
  }
}

// ---------------- K3: head-mean + LayerNorm + residual ----------------
__global__ __launch_bounds__(128) void k_final(
    const float* __restrict__ hp, const float* __restrict__ hin,
    const float* __restrict__ gamma, const float* __restrict__ beta,
    float* __restrict__ hout) {
  __shared__ float red[2][2];
  const int i = blockIdx.x;
  const int d = threadIdx.x;
  const float v = 0.25f * (hp[0 * (NN * 128) + i * 128 + d] +
                           hp[1 * (NN * 128) + i * 128 + d] +
                           hp[2 * (NN * 128) + i * 128 + d] +
                           hp[3 * (NN * 128) + i * 128 + d]);
  float s = v, sq = v * v;
#pragma unroll
  for (int off = 32; off >= 1; off >>= 1) {
    s += __shfl_xor(s, off, 64);
    sq += __shfl_xor(sq, off, 64);
  }
  const int w = d >> 6;
  if ((d & 63) == 0) { red[w][0] = s; red[w][1] = sq; }
  __syncthreads();
  s = red[0][0] + red[1][0];
  sq = red[0][1] + red[1][1];
  const float mu = s * (1.f / 128.f);
  const float var = sq * (1.f / 128.f) - mu * mu;
  const float hn = (v - mu) * rsqrtf(var + 1e-5f) * gamma[d] + beta[d];
  hout[i * 128 + d] = hin[i * 128 + d] + hn;
}

extern "C" void kernel_launch(void* const* d_in, const int* in_sizes, int n_in,
                              void* d_out, int out_size, void* d_ws, size_t ws_size,
                              hipStream_t stream) {
  const float* h     = (const float*)d_in[0];
  const int*   adj   = (const int*)d_in[1];
  const float* pos   = (const float*)d_in[2];
  const float* W     = (const float*)d_in[3];
  const float* a     = (const float*)d_in[4];
  const float* gamma = (const float*)d_in[5];
  const float* beta  = (const float*)d_in[6];
  float* out = (float*)d_out;
  float* ws  = (float*)d_ws;

  float* ht  = ws;                   // 4*N*128
  float* hp  = ws + 4 * NN * 128;    // 4*N*128
  float* src = ws + 8 * NN * 128;    // 4*N
  float* tgt = src + 4 * NN;         // 4*N

  k_htgemm<<<NN / 16, 512, 0, stream>>>(h, W, ht);
  k_srctgt<<<HH * NN, 64, 0, stream>>>(ht, a, src, tgt);
  k_attn<<<NN / BI, 256, 0, stream>>>(ht, adj, pos, src, tgt, hp, out + NN * 128);
  k_final<<<NN, 128, 0, stream>>>(hp, h, gamma, beta, out);
}

// Round 2
// 375.371 us; speedup vs baseline: 1.2278x; 1.2278x over previous
//
#include <hip/hip_runtime.h>
#include <math.h>

#define NN 4096
#define HH 4

typedef _Float16 h4 __attribute__((ext_vector_type(4)));
typedef float f4 __attribute__((ext_vector_type(4)));

// ---------------- K1: htT16[h][d][j] = fp16((h@W)[j][h*128+d]) ----------------
__global__ __launch_bounds__(512) void k_htgemm(const float* __restrict__ h,
                                                const float* __restrict__ W,
                                                _Float16* __restrict__ htT) {
  __shared__ float hs[16][128];
  const int i0 = blockIdx.x * 16;
  for (int idx = threadIdx.x; idx < 16 * 128; idx += 512)
    hs[idx >> 7][idx & 127] = h[(i0 + (idx >> 7)) * 128 + (idx & 127)];
  __syncthreads();
  const int c = threadIdx.x;  // output column 0..511
  float acc[16];
#pragma unroll
  for (int r = 0; r < 16; ++r) acc[r] = 0.f;
  for (int k = 0; k < 128; ++k) {
    const float w = W[k * 512 + c];
#pragma unroll
    for (int r = 0; r < 16; ++r) acc[r] = fmaf(hs[r][k], w, acc[r]);
  }
  const int hc = c >> 7, d = c & 127;
  _Float16* dst = htT + (hc * 128 + d) * NN + i0;
#pragma unroll
  for (int g = 0; g < 4; ++g) {
    h4 v;
    v.x = (_Float16)acc[g * 4 + 0];
    v.y = (_Float16)acc[g * 4 + 1];
    v.z = (_Float16)acc[g * 4 + 2];
    v.w = (_Float16)acc[g * 4 + 3];
    *(h4*)(dst + g * 4) = v;
  }
}

// ---------------- K2: src/tgt from htT16 ----------------
__global__ __launch_bounds__(256) void k_srctgt(const _Float16* __restrict__ htT,
                                                const float* __restrict__ a,
                                                float* __restrict__ src,
                                                float* __restrict__ tgt) {
  const int b = blockIdx.x;      // 64 blocks: h = b>>4, chunk = b&15
  const int hh = b >> 4;
  const int i = (b & 15) * 256 + threadIdx.x;
  const _Float16* base = htT + hh * 128 * NN + i;
  float s = 0.f, t = 0.f;
#pragma unroll 8
  for (int d = 0; d < 128; ++d) {
    const float v = (float)base[d * NN];
    s = fmaf(v, a[hh * 256 + d], s);
    t = fmaf(v, a[hh * 256 + 128 + d], t);
  }
  src[hh * NN + i] = s;
  tgt[hh * NN + i] = t;
}

// ---------------- K3: posT16[16][N] (rows 0..2 = xyz, rest 0) ----------------
__global__ __launch_bounds__(256) void k_posT(const float* __restrict__ pos,
                                              _Float16* __restrict__ posT) {
  const int idx = blockIdx.x * 256 + threadIdx.x;  // 65536
  const int r = idx >> 12, j = idx & 4095;
  posT[r * NN + j] = (_Float16)(r < 3 ? pos[j * 3 + r] : 0.f);
}

// ---------------- K4: pass1 — per-(h,i) softmax max M and 1/sum Li ----------------
__global__ __launch_bounds__(256) void k_pass1(const int* __restrict__ adj,
                                               const float* __restrict__ pos,
                                               const float* __restrict__ src,
                                               const float* __restrict__ tgt,
                                               float* __restrict__ M,
                                               float* __restrict__ Li) {
  const int i0 = blockIdx.x * 4;  // 1024 blocks, 4 rows each
  const int tid = threadIdx.x;
  float px[4], py[4], pz[4], sv[4][HH];
#pragma unroll
  for (int r = 0; r < 4; ++r) {
    px[r] = pos[(i0 + r) * 3];
    py[r] = pos[(i0 + r) * 3 + 1];
    pz[r] = pos[(i0 + r) * 3 + 2];
#pragma unroll
    for (int hh = 0; hh < HH; ++hh) sv[r][hh] = src[hh * NN + i0 + r];
  }
  float m[4][HH], l[4][HH];
#pragma unroll
  for (int r = 0; r < 4; ++r)
#pragma unroll
    for (int hh = 0; hh < HH; ++hh) { m[r][hh] = -3e38f; l[r][hh] = 0.f; }

  for (int j = tid; j < NN; j += 256) {
    const float qx = pos[j * 3], qy = pos[j * 3 + 1], qz = pos[j * 3 + 2];
    float tj[HH];
#pragma unroll
    for (int hh = 0; hh < HH; ++hh) tj[hh] = tgt[hh * NN + j];
#pragma unroll
    for (int r = 0; r < 4; ++r) {
      const int av = adj[(i0 + r) * NN + j];
      const float dx = px[r] - qx, dy = py[r] - qy, dz = pz[r] - qz;
      const float dist = sqrtf(dx * dx + dy * dy + dz * dz);
      const float dm = av > 0 ? dist : 1e30f;
#pragma unroll
      for (int hh = 0; hh < HH; ++hh) {
        float e = sv[r][hh] + tj[hh] - dm;
        e = fmaxf(e, 0.2f * e);
        const float nm = fmaxf(m[r][hh], e);
        l[r][hh] = l[r][hh] * __expf(m[r][hh] - nm) + __expf(e - nm);
        m[r][hh] = nm;
      }
    }
  }
  // wave butterfly
#pragma unroll
  for (int off = 32; off >= 1; off >>= 1) {
#pragma unroll
    for (int r = 0; r < 4; ++r)
#pragma unroll
      for (int hh = 0; hh < HH; ++hh) {
        const float om = __shfl_xor(m[r][hh], off, 64);
        const float ol = __shfl_xor(l[r][hh], off, 64);
        const float nm = fmaxf(m[r][hh], om);
        l[r][hh] = l[r][hh] * __expf(m[r][hh] - nm) + ol * __expf(om - nm);
        m[r][hh] = nm;
      }
  }
  __shared__ float red[4][4][HH][2];
  const int wid = tid >> 6;
  if ((tid & 63) == 0) {
#pragma unroll
    for (int r = 0; r < 4; ++r)
#pragma unroll
      for (int hh = 0; hh < HH; ++hh) {
        red[wid][r][hh][0] = m[r][hh];
        red[wid][r][hh][1] = l[r][hh];
      }
  }
  __syncthreads();
  if (tid < 16) {
    const int r = tid >> 2, hh = tid & 3;
    float mm = red[0][r][hh][0], ll = red[0][r][hh][1];
#pragma unroll
    for (int w = 1; w < 4; ++w) {
      const float om = red[w][r][hh][0], ol = red[w][r][hh][1];
      const float nm = fmaxf(mm, om);
      ll = ll * __expf(mm - nm) + ol * __expf(om - nm);
      mm = nm;
    }
    M[hh * NN + i0 + r] = mm;
    Li[hh * NN + i0 + r] = 1.f / ll;
  }
}

// ---------------- K5: pass2 — p recompute + MFMA PV + pos update ----------------
__global__ __launch_bounds__(512) void k_pass2(
    const _Float16* __restrict__ htT, const _Float16* __restrict__ posT,
    const int* __restrict__ adj, const float* __restrict__ pos,
    const float* __restrict__ src, const float* __restrict__ tgt,
    const float* __restrict__ Mg, const float* __restrict__ Lig,
    float* __restrict__ hp, float* __restrict__ out_pos) {
  __shared__ __attribute__((aligned(16))) float smem[4 * 16 * 128 + 8 * 16 * 16];
  float* distm = smem;             // [2][16][68]
  float* tgts = smem + 2 * 16 * 68;  // [2][4][68]

  const int tid = threadIdx.x;
  const int i0 = blockIdx.x * 16;
  const int w = tid >> 6, lane = tid & 63;
  const int hh = w & 3, jp = w >> 2;
  const int il = lane & 15, kg = lane >> 4;

  const float srcv = src[hh * NN + i0 + il];
  const float Mv = Mg[hh * NN + i0 + il];
  const float Liv = Lig[hh * NN + i0 + il];

  // dist-staging role constants (threads 0..255)
  float pix[4], piy[4], piz[4];
  {
    const int ig = (tid >> 6) & 3;
#pragma unroll
    for (int q = 0; q < 4; ++q) {
      const int i = ig * 4 + q;
      pix[q] = pos[(i0 + i) * 3];
      piy[q] = pos[(i0 + i) * 3 + 1];
      piz[q] = pos[(i0 + i) * 3 + 2];
    }
  }

  f4 acc[8];
#pragma unroll
  for (int dt = 0; dt < 8; ++dt) acc[dt] = (f4){0.f, 0.f, 0.f, 0.f};
  f4 pacc = (f4){0.f, 0.f, 0.f, 0.f};

  const _Float16* bbase = htT + (hh * 128 + il) * NN + kg * 4;
  const _Float16* pbase = posT + il * NN + kg * 4;

  for (int tp = 0; tp < 32; ++tp) {
#pragma unroll
    for (int tb = 0; tb < 2; ++tb) {
      const int j0 = (tp * 2 + tb) * 64;
      if (tid < 256) {
        const int jj = tid & 63, ig = tid >> 6;
        const int j = j0 + jj;
        const float qx = pos[j * 3], qy = pos[j * 3 + 1], qz = pos[j * 3 + 2];
#pragma unroll
        for (int q = 0; q < 4; ++q) {
          const int i = ig * 4 + q;
          const int av = adj[(i0 + i) * NN + j];
          const float dx = pix[q] - qx, dy = piy[q] - qy, dz = piz[q] - qz;
          const float dist = sqrtf(dx * dx + dy * dy + dz * dz);
          distm[(tb * 16 + i) * 68 + jj] = av > 0 ? dist : 1e30f;
        }
      } else {
        const int t2 = tid - 256;
        const int jj = t2 & 63, hx = t2 >> 6;
        tgts[(tb * 4 + hx) * 68 + jj] = tgt[hx * NN + j0 + jj];
      }
    }
    __syncthreads();
    {
      const int j0 = (tp * 2 + jp) * 64;
      h4 af[4];
#pragma unroll
      for (int ks = 0; ks < 4; ++ks) {
        const float4 dd = *(const float4*)&distm[(jp * 16 + il) * 68 + ks * 16 + kg * 4];
        const float4 tt = *(const float4*)&tgts[(jp * 4 + hh) * 68 + ks * 16 + kg * 4];
        float e0 = srcv + tt.x - dd.x; e0 = fmaxf(e0, 0.2f * e0);
        float e1 = srcv + tt.y - dd.y; e1 = fmaxf(e1, 0.2f * e1);
        float e2 = srcv + tt.z - dd.z; e2 = fmaxf(e2, 0.2f * e2);
        float e3 = srcv + tt.w - dd.w; e3 = fmaxf(e3, 0.2f * e3);
        h4 p;
        p.x = (_Float16)(__expf(e0 - Mv) * Liv);
        p.y = (_Float16)(__expf(e1 - Mv) * Liv);
        p.z = (_Float16)(__expf(e2 - Mv) * Liv);
        p.w = (_Float16)(__expf(e3 - Mv) * Liv);
        af[ks] = p;
      }
      const _Float16* bb = bbase + j0;
#pragma unroll
      for (int dt = 0; dt < 8; ++dt) {
#pragma unroll
        for (int ks = 0; ks < 4; ++ks) {
          const h4 bv = *(const h4*)(bb + dt * 16 * NN + ks * 16);
          acc[dt] = __builtin_amdgcn_mfma_f32_16x16x16f16(af[ks], bv, acc[dt], 0, 0, 0);
        }
      }
      const _Float16* pb = pbase + j0;
#pragma unroll
      for (int ks = 0; ks < 4; ++ks) {
        const h4 pv = *(const h4*)(pb + ks * 16);
        pacc = __builtin_amdgcn_mfma_f32_16x16x16f16(af[ks], pv, pacc, 0, 0, 0);
      }
    }
    __syncthreads();
  }

  // ---- epilogue (LDS reused) ----
  float* acc_s = smem;                  // [4][16][128]
  float* pacc_s = smem + 4 * 16 * 128;  // [4][2][16][16]
#pragma unroll
  for (int r = 0; r < 4; ++r)
    pacc_s[((hh * 2 + jp) * 16 + kg * 4 + r) * 16 + il] = pacc[r];
  if (jp == 1) {
#pragma unroll
    for (int dt = 0; dt < 8; ++dt)
#pragma unroll
      for (int r = 0; r < 4; ++r)
        acc_s[(hh * 16 + kg * 4 + r) * 128 + dt * 16 + il] = acc[dt][r];
  }
  __syncthreads();
  if (jp == 0) {
#pragma unroll
    for (int dt = 0; dt < 8; ++dt)
#pragma unroll
      for (int r = 0; r < 4; ++r) {
        const float v = acc[dt][r] + acc_s[(hh * 16 + kg * 4 + r) * 128 + dt * 16 + il];
        hp[hh * (NN * 128) + (i0 + kg * 4 + r) * 128 + dt * 16 + il] = v;
      }
  }
  if (tid < 48) {
    const int c = tid >> 4, i = tid & 15;
    float s = 0.f;
#pragma unroll
    for (int z = 0; z < 8; ++z) s += pacc_s[(z * 16 + i) * 16 + c];
    out_pos[(i0 + i) * 3 + c] = 2.f * pos[(i0 + i) * 3 + c] - 0.25f * s;
  }
}

// ---------------- K6: head-mean + LayerNorm + residual ----------------
__global__ __launch_bounds__(128) void k_final(
    const float* __restrict__ hp, const float* __restrict__ hin,
    const float* __restrict__ gamma, const float* __restrict__ beta,
    float* __restrict__ hout) {
  __shared__ float red[2][2];
  const int i = blockIdx.x;
  const int d = threadIdx.x;
  const float v = 0.25f * (hp[0 * (NN * 128) + i * 128 + d] +
                           hp[1 * (NN * 128) + i * 128 + d] +
                           hp[2 * (NN * 128) + i * 128 + d] +
                           hp[3 * (NN * 128) + i * 128 + d]);
  float s = v, sq = v * v;
#pragma unroll
  for (int off = 32; off >= 1; off >>= 1) {
    s += __shfl_xor(s, off, 64);
    sq += __shfl_xor(sq, off, 64);
  }
  const int w = d >> 6;
  if ((d & 63) == 0) { red[w][0] = s; red[w][1] = sq; }
  __syncthreads();
  s = red[0][0] + red[1][0];
  sq = red[0][1] + red[1][1];
  const float mu = s * (1.f / 128.f);
  const float var = sq * (1.f / 128.f) - mu * mu;
  const float hn = (v - mu) * rsqrtf(var + 1e-5f) * gamma[d] + beta[d];
  hout[i * 128 + d] = hin[i * 128 + d] + hn;
}

extern "C" void kernel_launch(void* const* d_in, const int* in_sizes, int n_in,
                              void* d_out, int out_size, void* d_ws, size_t ws_size,
                              hipStream_t stream) {
  const float* h     = (const float*)d_in[0];
  const int*   adj   = (const int*)d_in[1];
  const float* pos   = (const float*)d_in[2];
  const float* W     = (const float*)d_in[3];
  const float* a     = (const float*)d_in[4];
  const float* gamma = (const float*)d_in[5];
  const float* beta  = (const float*)d_in[6];
  float* out = (float*)d_out;

  _Float16* htT  = (_Float16*)d_ws;            // 4*128*4096 halves = 4 MB
  _Float16* posT = htT + 4 * 128 * NN;         // 16*4096 halves = 128 KB
  float* fws = (float*)(posT + 16 * NN);
  float* src = fws;                 // 16384
  float* tgt = src + HH * NN;       // 16384
  float* M   = tgt + HH * NN;       // 16384
  float* Li  = M + HH * NN;         // 16384
  float* hp  = Li + HH * NN;        // 4*4096*128 = 8 MB

  k_htgemm<<<NN / 16, 512, 0, stream>>>(h, W, htT);
  k_srctgt<<<64, 256, 0, stream>>>(htT, a, src, tgt);
  k_posT<<<256, 256, 0, stream>>>(pos, posT);
  k_pass1<<<NN / 4, 256, 0, stream>>>(adj, pos, src, tgt, M, Li);
  k_pass2<<<NN / 16, 512, 0, stream>>>(htT, posT, adj, pos, src, tgt, M, Li, hp,
                                       out + NN * 128);
  k_final<<<NN, 128, 0, stream>>>(hp, h, gamma, beta, out);
}

// Round 3
// 297.718 us; speedup vs baseline: 1.5481x; 1.2608x over previous
//
#include <hip/hip_runtime.h>
#include <math.h>

#define NN 4096
#define HH 4

typedef _Float16 h4 __attribute__((ext_vector_type(4)));
typedef float f4 __attribute__((ext_vector_type(4)));

// ---------------- K1: htT16[h][d][j] = fp16((h@W)[j][h*128+d]) ----------------
__global__ __launch_bounds__(512) void k_htgemm(const float* __restrict__ h,
                                                const float* __restrict__ W,
                                                _Float16* __restrict__ htT) {
  __shared__ float hs[16][128];
  const int i0 = blockIdx.x * 16;
  for (int idx = threadIdx.x; idx < 16 * 128; idx += 512)
    hs[idx >> 7][idx & 127] = h[(i0 + (idx >> 7)) * 128 + (idx & 127)];
  __syncthreads();
  const int c = threadIdx.x;  // output column 0..511
  float acc[16];
#pragma unroll
  for (int r = 0; r < 16; ++r) acc[r] = 0.f;
  for (int k = 0; k < 128; ++k) {
    const float w = W[k * 512 + c];
#pragma unroll
    for (int r = 0; r < 16; ++r) acc[r] = fmaf(hs[r][k], w, acc[r]);
  }
  const int hc = c >> 7, d = c & 127;
  _Float16* dst = htT + (hc * 128 + d) * NN + i0;
#pragma unroll
  for (int g = 0; g < 4; ++g) {
    h4 v;
    v.x = (_Float16)acc[g * 4 + 0];
    v.y = (_Float16)acc[g * 4 + 1];
    v.z = (_Float16)acc[g * 4 + 2];
    v.w = (_Float16)acc[g * 4 + 3];
    *(h4*)(dst + g * 4) = v;
  }
}

// ---------------- K2: src/tgt from htT16 ----------------
__global__ __launch_bounds__(256) void k_srctgt(const _Float16* __restrict__ htT,
                                                const float* __restrict__ a,
                                                float* __restrict__ src,
                                                float* __restrict__ tgt) {
  const int b = blockIdx.x;      // 64 blocks: h = b>>4, chunk = b&15
  const int hh = b >> 4;
  const int i = (b & 15) * 256 + threadIdx.x;
  const _Float16* base = htT + hh * 128 * NN + i;
  float s = 0.f, t = 0.f;
#pragma unroll 8
  for (int d = 0; d < 128; ++d) {
    const float v = (float)base[d * NN];
    s = fmaf(v, a[hh * 256 + d], s);
    t = fmaf(v, a[hh * 256 + 128 + d], t);
  }
  src[hh * NN + i] = s;
  tgt[hh * NN + i] = t;
}

// ---------------- K3: posT16[16][N] rows 0..2 = xyz, row 3 = 1, rest 0 ----------------
__global__ __launch_bounds__(256) void k_posT(const float* __restrict__ pos,
                                              _Float16* __restrict__ posT) {
  const int idx = blockIdx.x * 256 + threadIdx.x;  // 65536
  const int r = idx >> 12, j = idx & 4095;
  float v = 0.f;
  if (r < 3) v = pos[j * 3 + r];
  else if (r == 3) v = 1.f;
  posT[r * NN + j] = (_Float16)v;
}

// ---------------- K4: single-pass unnormalized attention + MFMA ----------------
__global__ __launch_bounds__(512, 4) void k_attn(
    const _Float16* __restrict__ htT, const _Float16* __restrict__ posT,
    const int* __restrict__ adj, const float* __restrict__ pos,
    const float* __restrict__ src, const float* __restrict__ tgt,
    float* __restrict__ hp_part, float* __restrict__ ppart) {
  __shared__ __attribute__((aligned(16))) float smem[4 * 16 * 128 + 512];
  float* distm = smem;                  // staging: [2][16][132]
  float* tgts  = smem + 2 * 16 * 132;   // staging: [2][4][132]
  float* acc_s  = smem;                 // epilogue: [4][16][128]
  float* pacc_s = smem + 4 * 16 * 128;  // epilogue: [4][2][16][4]

  const int tid = threadIdx.x;
  const int ib = (int)blockIdx.x >> 1, jh = (int)blockIdx.x & 1;
  const int i0 = ib * 16;
  const int jbase = jh * 2048;
  const int w = tid >> 6, lane = tid & 63;
  const int hh = w & 3, jp = w >> 2;      // head, j-subtile
  const int il = lane & 15, kg = lane >> 4;

  const float srcv = src[hh * NN + i0 + il];

  // staging role: thread stages rows ig*4..ig*4+3 at column jj of each 128-tile
  const int jj = tid & 127, ig = tid >> 7;
  float pix[4], piy[4], piz[4];
#pragma unroll
  for (int q = 0; q < 4; ++q) {
    pix[q] = pos[(i0 + ig * 4 + q) * 3 + 0];
    piy[q] = pos[(i0 + ig * 4 + q) * 3 + 1];
    piz[q] = pos[(i0 + ig * 4 + q) * 3 + 2];
  }
  const float* posb = pos + (jbase + jj) * 3;
  const float* tgtb = tgt + ig * NN + jbase + jj;
  const int*   adjb = adj + (i0 + ig * 4) * NN + jbase + jj;

  const _Float16* bbase = htT + (hh * 128 + il) * NN + jbase + jp * 64 + kg * 4;
  const _Float16* pbase = posT + il * NN + jbase + jp * 64 + kg * 4;

  f4 acc[8];
#pragma unroll
  for (int dt = 0; dt < 8; ++dt) acc[dt] = (f4){0.f, 0.f, 0.f, 0.f};
  f4 pacc = (f4){0.f, 0.f, 0.f, 0.f};

  float qx, qy, qz, tgv;
  int adjv[4];

#define LOADT(t)                        \
  {                                     \
    qx = posb[(t) * 384 + 0];           \
    qy = posb[(t) * 384 + 1];           \
    qz = posb[(t) * 384 + 2];           \
    tgv = tgtb[(t) * 128];              \
    adjv[0] = adjb[0 * NN + (t) * 128]; \
    adjv[1] = adjb[1 * NN + (t) * 128]; \
    adjv[2] = adjb[2 * NN + (t) * 128]; \
    adjv[3] = adjb[3 * NN + (t) * 128]; \
  }

#define WRITET(b)                                                        \
  {                                                                      \
    float* db = distm + (b) * 2112;                                      \
    _Pragma("unroll") for (int q = 0; q < 4; ++q) {                      \
      const float dx = pix[q] - qx, dy = piy[q] - qy, dz = piz[q] - qz;  \
      const float dist = sqrtf(dx * dx + dy * dy + dz * dz);             \
      db[(ig * 4 + q) * 132 + jj] = adjv[q] > 0 ? dist : 1e30f;          \
    }                                                                    \
    tgts[(b) * 528 + ig * 132 + jj] = tgv;                               \
  }

  LOADT(0);
  WRITET(0);
  LOADT(1);
  __syncthreads();

  for (int tp = 0; tp < 16; ++tp) {
    const int buf = tp & 1;
    // ---- compute tile tp ----
    const float* dmb = distm + buf * 2112 + il * 132 + jp * 64;
    const float* ttb = tgts + buf * 528 + hh * 132 + jp * 64;
    h4 af[4];
#pragma unroll
    for (int ks = 0; ks < 4; ++ks) {
      const float4 dd = *(const float4*)(dmb + ks * 16 + kg * 4);
      const float4 tt = *(const float4*)(ttb + ks * 16 + kg * 4);
      float e0 = srcv + tt.x - dd.x; e0 = fmaxf(e0, 0.2f * e0);
      float e1 = srcv + tt.y - dd.y; e1 = fmaxf(e1, 0.2f * e1);
      float e2 = srcv + tt.z - dd.z; e2 = fmaxf(e2, 0.2f * e2);
      float e3 = srcv + tt.w - dd.w; e3 = fmaxf(e3, 0.2f * e3);
      h4 p;
      p.x = (_Float16)__expf(e0);
      p.y = (_Float16)__expf(e1);
      p.z = (_Float16)__expf(e2);
      p.w = (_Float16)__expf(e3);
      af[ks] = p;
    }
    const _Float16* bb = bbase + tp * 128;
#pragma unroll
    for (int dt = 0; dt < 8; ++dt) {
#pragma unroll
      for (int ks = 0; ks < 4; ++ks) {
        const h4 bv = *(const h4*)(bb + dt * 16 * NN + ks * 16);
        acc[dt] = __builtin_amdgcn_mfma_f32_16x16x16f16(af[ks], bv, acc[dt], 0, 0, 0);
      }
    }
    const _Float16* pb = pbase + tp * 128;
#pragma unroll
    for (int ks = 0; ks < 4; ++ks) {
      const h4 pv = *(const h4*)(pb + ks * 16);
      pacc = __builtin_amdgcn_mfma_f32_16x16x16f16(af[ks], pv, pacc, 0, 0, 0);
    }
    // ---- write prefetched tile tp+1 (loads issued last iter; vmcnt overlaps) ----
    if (tp + 1 < 16) WRITET((tp + 1) & 1);
    // ---- issue loads for tile tp+2 ----
    if (tp + 2 < 16) LOADT(tp + 2);
    __syncthreads();
  }
#undef LOADT
#undef WRITET

  // ---- epilogue: combine jp halves, write partials ----
  if (il < 4) {
#pragma unroll
    for (int r = 0; r < 4; ++r)
      pacc_s[hh * 128 + jp * 64 + (kg * 4 + r) * 4 + il] = pacc[r];
  }
  if (jp == 1) {
#pragma unroll
    for (int dt = 0; dt < 8; ++dt)
#pragma unroll
      for (int r = 0; r < 4; ++r)
        acc_s[(hh * 16 + kg * 4 + r) * 128 + dt * 16 + il] = acc[dt][r];
  }
  __syncthreads();
  if (jp == 0) {
    float* hpb = hp_part + ((jh * 4 + hh) * NN + i0) * 128;
#pragma unroll
    for (int dt = 0; dt < 8; ++dt)
#pragma unroll
      for (int r = 0; r < 4; ++r)
        hpb[(kg * 4 + r) * 128 + dt * 16 + il] =
            acc[dt][r] + acc_s[(hh * 16 + kg * 4 + r) * 128 + dt * 16 + il];
  }
  if (tid < 256) {
    const int c = tid & 3, i2 = (tid >> 2) & 15, h2 = tid >> 6;
    ppart[((jh * 4 + h2) * NN + i0 + i2) * 4 + c] =
        pacc_s[h2 * 128 + i2 * 4 + c] + pacc_s[h2 * 128 + 64 + i2 * 4 + c];
  }
}

// ---------------- K5: normalize + head-mean + LayerNorm + residual + pos ----------------
__global__ __launch_bounds__(128) void k_finish(
    const float* __restrict__ hp_part, const float* __restrict__ ppart,
    const float* __restrict__ hin, const float* __restrict__ pos,
    const float* __restrict__ gamma, const float* __restrict__ beta,
    float* __restrict__ hout, float* __restrict__ out_pos) {
  __shared__ float red[2][2];
  const int i = blockIdx.x, d = threadIdx.x;
  float Li[4];
  float v = 0.f;
#pragma unroll
  for (int hx = 0; hx < 4; ++hx) {
    Li[hx] = 1.f / (ppart[(hx * NN + i) * 4 + 3] + ppart[((4 + hx) * NN + i) * 4 + 3]);
    v += (hp_part[(hx * NN + i) * 128 + d] + hp_part[((4 + hx) * NN + i) * 128 + d]) * Li[hx];
  }
  v *= 0.25f;
  float s = v, sq = v * v;
#pragma unroll
  for (int off = 32; off >= 1; off >>= 1) {
    s += __shfl_xor(s, off, 64);
    sq += __shfl_xor(sq, off, 64);
  }
  const int wv = d >> 6;
  if ((d & 63) == 0) { red[wv][0] = s; red[wv][1] = sq; }
  __syncthreads();
  s = red[0][0] + red[1][0];
  sq = red[0][1] + red[1][1];
  const float mu = s * (1.f / 128.f);
  const float var = sq * (1.f / 128.f) - mu * mu;
  const float hn = (v - mu) * rsqrtf(var + 1e-5f) * gamma[d] + beta[d];
  hout[i * 128 + d] = hin[i * 128 + d] + hn;
  if (d < 3) {
    float sp = 0.f;
#pragma unroll
    for (int hx = 0; hx < 4; ++hx)
      sp += (ppart[(hx * NN + i) * 4 + d] + ppart[((4 + hx) * NN + i) * 4 + d]) * Li[hx];
    out_pos[i * 3 + d] = 2.f * pos[i * 3 + d] - 0.25f * sp;
  }
}

extern "C" void kernel_launch(void* const* d_in, const int* in_sizes, int n_in,
                              void* d_out, int out_size, void* d_ws, size_t ws_size,
                              hipStream_t stream) {
  const float* h     = (const float*)d_in[0];
  const int*   adj   = (const int*)d_in[1];
  const float* pos   = (const float*)d_in[2];
  const float* W     = (const float*)d_in[3];
  const float* a     = (const float*)d_in[4];
  const float* gamma = (const float*)d_in[5];
  const float* beta  = (const float*)d_in[6];
  float* out = (float*)d_out;

  _Float16* htT  = (_Float16*)d_ws;            // 4*128*4096 halves = 4 MB
  _Float16* posT = htT + 4 * 128 * NN;         // 16*4096 halves = 128 KB
  float* fws = (float*)(posT + 16 * NN);
  float* src = fws;                            // 4*N
  float* tgt = src + HH * NN;                  // 4*N
  float* hp_part = tgt + HH * NN;              // 2*4*N*128 = 16 MB
  float* ppart = hp_part + 8 * NN * 128;       // 2*4*N*4 = 512 KB

  k_htgemm<<<NN / 16, 512, 0, stream>>>(h, W, htT);
  k_srctgt<<<64, 256, 0, stream>>>(htT, a, src, tgt);
  k_posT<<<256, 256, 0, stream>>>(pos, posT);
  k_attn<<<512, 512, 0, stream>>>(htT, posT, adj, pos, src, tgt, hp_part, ppart);
  k_finish<<<NN, 128, 0, stream>>>(hp_part, ppart, h, pos, gamma, beta, out,
                                   out + NN * 128);
}

// Round 4
// 165.763 us; speedup vs baseline: 2.7804x; 1.7960x over previous
//
#include <hip/hip_runtime.h>
#include <math.h>

#define NN 4096
#define HH 4

typedef _Float16 h4 __attribute__((ext_vector_type(4)));
typedef float f4 __attribute__((ext_vector_type(4)));

// ---------------- K1: htT16[h][d][j] = fp16((h@W)[j][h*128+d]) ----------------
__global__ __launch_bounds__(512) void k_htgemm(const float* __restrict__ h,
                                                const float* __restrict__ W,
                                                _Float16* __restrict__ htT) {
  __shared__ float hs[16][128];
  const int i0 = blockIdx.x * 16;
  for (int idx = threadIdx.x; idx < 16 * 128; idx += 512)
    hs[idx >> 7][idx & 127] = h[(i0 + (idx >> 7)) * 128 + (idx & 127)];
  __syncthreads();
  const int c = threadIdx.x;  // output column 0..511
  float acc[16];
#pragma unroll
  for (int r = 0; r < 16; ++r) acc[r] = 0.f;
  for (int k = 0; k < 128; ++k) {
    const float w = W[k * 512 + c];
#pragma unroll
    for (int r = 0; r < 16; ++r) acc[r] = fmaf(hs[r][k], w, acc[r]);
  }
  const int hc = c >> 7, d = c & 127;
  _Float16* dst = htT + (hc * 128 + d) * NN + i0;
#pragma unroll
  for (int g = 0; g < 4; ++g) {
    h4 v;
    v.x = (_Float16)acc[g * 4 + 0];
    v.y = (_Float16)acc[g * 4 + 1];
    v.z = (_Float16)acc[g * 4 + 2];
    v.w = (_Float16)acc[g * 4 + 3];
    *(h4*)(dst + g * 4) = v;
  }
}

// ---------------- K2: src/tgt from htT16 ----------------
__global__ __launch_bounds__(256) void k_srctgt(const _Float16* __restrict__ htT,
                                                const float* __restrict__ a,
                                                float* __restrict__ src,
                                                float* __restrict__ tgt) {
  const int b = blockIdx.x;      // 64 blocks: h = b>>4, chunk = b&15
  const int hh = b >> 4;
  const int i = (b & 15) * 256 + threadIdx.x;
  const _Float16* base = htT + hh * 128 * NN + i;
  float s = 0.f, t = 0.f;
#pragma unroll 8
  for (int d = 0; d < 128; ++d) {
    const float v = (float)base[d * NN];
    s = fmaf(v, a[hh * 256 + d], s);
    t = fmaf(v, a[hh * 256 + 128 + d], t);
  }
  src[hh * NN + i] = s;
  tgt[hh * NN + i] = t;
}

// ---------------- K3: fused attention, V staged via LDS ----------------
// LDS map (bytes):
//   [0, 131072)        Vs[2][512 rows][128 B]  fp16, 16B-chunk XOR-swizzled
//   [131072, 139776)   dist[2][64][17] f32 (transposed: [j][i], pad 17)
//   [139776, 141952)   tgts[2][4][68] f32
//   [141952, 146560)   ps[2][16][72] fp16 (rows 0..2 = xyz, 3 = 1, 4..15 = 0)
#define VS_OFF 0
#define DIST_OFF 131072
#define TGTS_OFF 139776
#define PS_OFF 141952
#define SMEM_BYTES 146560

__global__ __launch_bounds__(512, 2) void k_attn(
    const _Float16* __restrict__ htT, const int* __restrict__ adj,
    const float* __restrict__ pos, const float* __restrict__ src,
    const float* __restrict__ tgt, float* __restrict__ hp_part,
    float* __restrict__ ppart) {
  __shared__ __attribute__((aligned(16))) unsigned char smem[SMEM_BYTES];
  float* dist_s = (float*)(smem + DIST_OFF);     // buf stride 1088 floats
  float* tgts   = (float*)(smem + TGTS_OFF);     // buf stride 272 floats
  _Float16* ps  = (_Float16*)(smem + PS_OFF);    // buf stride 1152 halves

  const int tid = threadIdx.x;
  const int ib = (int)blockIdx.x >> 1, jh = (int)blockIdx.x & 1;
  const int i0 = ib * 16;
  const int jbase = jh * 2048;

  const int w = tid >> 6, lane = tid & 63;
  const int hh = w & 3, dp = w >> 2;       // head, d-half
  const int il = lane & 15, kg = lane >> 4;

  const float srcv = src[hh * NN + i0 + il];

  // ---- staging role constants ----
  const int jj = tid & 63;   // j within tile
  const int ii2 = w;         // stage dist rows ii2 and ii2+8
  const float pax = pos[(i0 + ii2) * 3], pay = pos[(i0 + ii2) * 3 + 1],
              paz = pos[(i0 + ii2) * 3 + 2];
  const float pbx = pos[(i0 + ii2 + 8) * 3], pby = pos[(i0 + ii2 + 8) * 3 + 1],
              pbz = pos[(i0 + ii2 + 8) * 3 + 2];
  const int* adjA = adj + (size_t)(i0 + ii2) * NN + jbase;
  const int* adjB = adj + (size_t)(i0 + ii2 + 8) * NN + jbase;
  const float* posj = pos + (size_t)jbase * 3;

  // V staging: thread covers rows rbase+64q (q=0..7), 16B chunk p=tid&7
  const _Float16* vsrc = htT + (size_t)(tid >> 3) * NN + (size_t)(tid & 7) * 8 + jbase;
  const int vlds_base = ((tid >> 3) << 7) + (((tid & 7) ^ ((tid >> 3) & 7)) << 4);

  f4 acc[4];
#pragma unroll
  for (int dt = 0; dt < 4; ++dt) acc[dt] = (f4){0.f, 0.f, 0.f, 0.f};
  f4 pacc = (f4){0.f, 0.f, 0.f, 0.f};

  // ---- prologue: zero ps (both bufs), stage tile 0 ----
  for (int idx = tid; idx < 2 * 16 * 72; idx += 512)
    ((_Float16*)(smem + PS_OFF))[idx] = (_Float16)0.f;
  __syncthreads();
  {
    float4 v[8];
#pragma unroll
    for (int q = 0; q < 8; ++q) v[q] = *(const float4*)(vsrc + (size_t)q * 64 * NN);
    const int a0 = adjA[jj], a1 = adjB[jj];
    const float qx = posj[jj * 3], qy = posj[jj * 3 + 1], qz = posj[jj * 3 + 2];
    const float ex = (w < 4) ? tgt[w * NN + jbase + jj]
                             : (w == 4 ? qx : w == 5 ? qy : w == 6 ? qz : 1.f);
#pragma unroll
    for (int q = 0; q < 8; ++q)
      *(float4*)(smem + vlds_base + q * 8192) = v[q];
    float dx = pax - qx, dy = pay - qy, dz = paz - qz;
    const float dA = sqrtf(dx * dx + dy * dy + dz * dz);
    dist_s[jj * 17 + ii2] = a0 > 0 ? dA : 1e30f;
    dx = pbx - qx; dy = pby - qy; dz = pbz - qz;
    const float dB = sqrtf(dx * dx + dy * dy + dz * dz);
    dist_s[jj * 17 + ii2 + 8] = a1 > 0 ? dB : 1e30f;
    if (w < 4) tgts[w * 68 + jj] = ex;
    else ps[(w - 4) * 72 + jj] = (_Float16)ex;
  }
  __syncthreads();

  // ---- main loop: 32 tiles of 64 j ----
  for (int t = 0; t < 32; ++t) {
    const int cur = t & 1;
    float4 v[8];
    int a0 = 0, a1 = 0;
    float qx = 0.f, qy = 0.f, qz = 0.f, ex = 0.f;
    if (t < 31) {  // issue loads for tile t+1 (consumed after compute)
      const int jn = (t + 1) * 64 + jj;
#pragma unroll
      for (int q = 0; q < 8; ++q)
        v[q] = *(const float4*)(vsrc + (t + 1) * 64 + (size_t)q * 64 * NN);
      a0 = adjA[jn];
      a1 = adjB[jn];
      qx = posj[jn * 3]; qy = posj[jn * 3 + 1]; qz = posj[jn * 3 + 2];
      ex = (w < 4) ? tgt[w * NN + jbase + jn]
                   : (w == 4 ? qx : w == 5 ? qy : w == 6 ? qz : 1.f);
    }
    // ---- compute tile t ----
    {
      const float* dcur = dist_s + cur * 1088;
      const float* tcur = tgts + cur * 272 + hh * 68;
      h4 af[4];
#pragma unroll
      for (int ks = 0; ks < 4; ++ks) {
        const int jf = ks * 16 + kg * 4;
        const float4 tt = *(const float4*)(tcur + jf);
        const float d0 = dcur[(jf + 0) * 17 + il];
        const float d1 = dcur[(jf + 1) * 17 + il];
        const float d2 = dcur[(jf + 2) * 17 + il];
        const float d3 = dcur[(jf + 3) * 17 + il];
        float e0 = srcv + tt.x - d0; e0 = fmaxf(e0, 0.2f * e0);
        float e1 = srcv + tt.y - d1; e1 = fmaxf(e1, 0.2f * e1);
        float e2 = srcv + tt.z - d2; e2 = fmaxf(e2, 0.2f * e2);
        float e3 = srcv + tt.w - d3; e3 = fmaxf(e3, 0.2f * e3);
        h4 p;
        p.x = (_Float16)__expf(e0);
        p.y = (_Float16)__expf(e1);
        p.z = (_Float16)__expf(e2);
        p.w = (_Float16)__expf(e3);
        af[ks] = p;
      }
      const unsigned char* vb =
          smem + cur * 65536 + (size_t)(hh * 128 + dp * 64 + il) * 128;
#pragma unroll
      for (int dt = 0; dt < 4; ++dt) {
#pragma unroll
        for (int ks = 0; ks < 4; ++ks) {
          const h4 bv = *(const h4*)(vb + dt * 2048 +
                                     ((((ks << 1) | (kg >> 1)) ^ (il & 7)) << 4) +
                                     ((kg & 1) << 3));
          acc[dt] = __builtin_amdgcn_mfma_f32_16x16x16f16(af[ks], bv, acc[dt], 0, 0, 0);
        }
      }
      if (dp == 0) {
#pragma unroll
        for (int ks = 0; ks < 4; ++ks) {
          const h4 pv = *(const h4*)(smem + PS_OFF + cur * 2304 + il * 144 +
                                     ks * 32 + kg * 8);
          pacc = __builtin_amdgcn_mfma_f32_16x16x16f16(af[ks], pv, pacc, 0, 0, 0);
        }
      }
    }
    // ---- write stage tile t+1 into other buffer ----
    if (t < 31) {
      const int nxt = cur ^ 1;
#pragma unroll
      for (int q = 0; q < 8; ++q)
        *(float4*)(smem + nxt * 65536 + vlds_base + q * 8192) = v[q];
      float dx = pax - qx, dy = pay - qy, dz = paz - qz;
      const float dA = sqrtf(dx * dx + dy * dy + dz * dz);
      dist_s[nxt * 1088 + jj * 17 + ii2] = a0 > 0 ? dA : 1e30f;
      dx = pbx - qx; dy = pby - qy; dz = pbz - qz;
      const float dB = sqrtf(dx * dx + dy * dy + dz * dz);
      dist_s[nxt * 1088 + jj * 17 + ii2 + 8] = a1 > 0 ? dB : 1e30f;
      if (w < 4) tgts[nxt * 272 + w * 68 + jj] = ex;
      else ps[nxt * 1152 + (w - 4) * 72 + jj] = (_Float16)ex;
    }
    __syncthreads();
  }

  // ---- epilogue: direct global writes (dp halves are disjoint in d) ----
  float* hpb = hp_part + ((size_t)(jh * 4 + hh) * NN + i0) * 128 + dp * 64;
#pragma unroll
  for (int dt = 0; dt < 4; ++dt)
#pragma unroll
    for (int r = 0; r < 4; ++r)
      hpb[(kg * 4 + r) * 128 + dt * 16 + il] = acc[dt][r];
  if (dp == 0 && il < 4) {
#pragma unroll
    for (int r = 0; r < 4; ++r)
      ppart[((size_t)(jh * 4 + hh) * NN + i0 + kg * 4 + r) * 4 + il] = pacc[r];
  }
}

// ---------------- K5: normalize + head-mean + LayerNorm + residual + pos ----------------
__global__ __launch_bounds__(128) void k_finish(
    const float* __restrict__ hp_part, const float* __restrict__ ppart,
    const float* __restrict__ hin, const float* __restrict__ pos,
    const float* __restrict__ gamma, const float* __restrict__ beta,
    float* __restrict__ hout, float* __restrict__ out_pos) {
  __shared__ float red[2][2];
  const int i = blockIdx.x, d = threadIdx.x;
  float Li[4];
  float v = 0.f;
#pragma unroll
  for (int hx = 0; hx < 4; ++hx) {
    Li[hx] = 1.f / (ppart[(hx * NN + i) * 4 + 3] + ppart[((4 + hx) * NN + i) * 4 + 3]);
    v += (hp_part[(hx * NN + i) * 128 + d] + hp_part[((4 + hx) * NN + i) * 128 + d]) * Li[hx];
  }
  v *= 0.25f;
  float s = v, sq = v * v;
#pragma unroll
  for (int off = 32; off >= 1; off >>= 1) {
    s += __shfl_xor(s, off, 64);
    sq += __shfl_xor(sq, off, 64);
  }
  const int wv = d >> 6;
  if ((d & 63) == 0) { red[wv][0] = s; red[wv][1] = sq; }
  __syncthreads();
  s = red[0][0] + red[1][0];
  sq = red[0][1] + red[1][1];
  const float mu = s * (1.f / 128.f);
  const float var = sq * (1.f / 128.f) - mu * mu;
  const float hn = (v - mu) * rsqrtf(var + 1e-5f) * gamma[d] + beta[d];
  hout[i * 128 + d] = hin[i * 128 + d] + hn;
  if (d < 3) {
    float sp = 0.f;
#pragma unroll
    for (int hx = 0; hx < 4; ++hx)
      sp += (ppart[(hx * NN + i) * 4 + d] + ppart[((4 + hx) * NN + i) * 4 + d]) * Li[hx];
    out_pos[i * 3 + d] = 2.f * pos[i * 3 + d] - 0.25f * sp;
  }
}

extern "C" void kernel_launch(void* const* d_in, const int* in_sizes, int n_in,
                              void* d_out, int out_size, void* d_ws, size_t ws_size,
                              hipStream_t stream) {
  const float* h     = (const float*)d_in[0];
  const int*   adj   = (const int*)d_in[1];
  const float* pos   = (const float*)d_in[2];
  const float* W     = (const float*)d_in[3];
  const float* a     = (const float*)d_in[4];
  const float* gamma = (const float*)d_in[5];
  const float* beta  = (const float*)d_in[6];
  float* out = (float*)d_out;

  _Float16* htT = (_Float16*)d_ws;             // 4*128*4096 halves = 4 MB
  float* fws = (float*)(htT + 4 * 128 * NN);
  float* src = fws;                            // 4*N
  float* tgt = src + HH * NN;                  // 4*N
  float* hp_part = tgt + HH * NN;              // 2*4*N*128 = 16 MB
  float* ppart = hp_part + 8 * NN * 128;       // 2*4*N*4 = 512 KB

  k_htgemm<<<NN / 16, 512, 0, stream>>>(h, W, htT);
  k_srctgt<<<64, 256, 0, stream>>>(htT, a, src, tgt);
  k_attn<<<512, 512, 0, stream>>>(htT, adj, pos, src, tgt, hp_part, ppart);
  k_finish<<<NN, 128, 0, stream>>>(hp_part, ppart, h, pos, gamma, beta, out,
                                   out + NN * 128);
}